// Round 8
// baseline (83.776 us; speedup 1.0000x reference)
//
#include <hip/hip_runtime.h>

// Problem constants
#define BATCH 1024
#define C_CH  256
#define RR    49        // 7*7 spatial
#define SP    12544     // 256*49 per-batch patch elems; also FLAT
#define KVALID 625      // nonzero correlation outputs per batch
#define KPAD   640      // padded K for GEMM1
#define REP_N  1024

typedef __attribute__((ext_vector_type(4))) float f32x4;
typedef __attribute__((ext_vector_type(8))) short s16x8;   // 8 bf16 (4 VGPRs)

// ---- bf16 split helpers (RNE) ----
__device__ __forceinline__ unsigned short f2bf_rne(float f) {
    unsigned int u = __float_as_uint(f);
    unsigned int r = u + 0x7FFFu + ((u >> 16) & 1u);
    return (unsigned short)(r >> 16);
}
__device__ __forceinline__ float bf2f(unsigned short h) {
    return __uint_as_float(((unsigned int)h) << 16);
}
__device__ __forceinline__ void split2(float v, unsigned short& h, unsigned short& l) {
    h = f2bf_rne(v);
    l = f2bf_rne(v - bf2f(h));
}

// Decode index u in [0,25) -> (i, d), i,d in [0,7), i+d even.
__device__ __forceinline__ void dec25(int u, int& i, int& d) {
    int ii = (u >= 4) + (u >= 7) + (u >= 11) + (u >= 14) + (u >= 18) + (u >= 21);
    int cum = (7 * ii + 1) >> 1;
    i = ii;
    d = 2 * (u - cum) + (ii & 1);
}

// Compact index a in [0,640) -> flat column into W1's FLAT dim (a>=625 unused).
__device__ __forceinline__ int kflat_of(int a) {
    int ar = a / 25, ac = a % 25;
    int i, dy, j, dx;
    dec25(ar, i, dy);
    dec25(ac, j, dx);
    int pi = (dy + 16 - i) >> 1;
    int pj = (dx + 16 - j) >> 1;
    return (pi * 16 + pj) * 49 + i * 7 + j;
}

// ---------------------------------------------------------------------------
// Kernel 1: correlation -> compacted x [BATCH x KPAD] fp32 (zero-padded tail).
// EXACT R1 structure (empirically ~17 us): one block per batch, LDS-staged
// 64-channel fp32 chunks, scalar LDS reads + plain FMA. No split here.
// ---------------------------------------------------------------------------
__global__ __launch_bounds__(256) void corr_kernel(
    const float* __restrict__ p1, const float* __restrict__ p2,
    float* __restrict__ xo)
{
    __shared__ float s1[64 * RR];   // 12.25 KB
    __shared__ float s2[64 * RR];

    const int b = blockIdx.x;
    const int t = threadIdx.x;
    const float* P1 = p1 + (size_t)b * SP;
    const float* P2 = p2 + (size_t)b * SP;

    int ij[3], yx[3];
    #pragma unroll
    for (int s = 0; s < 3; ++s) {
        int a = t + s * 256;
        if (a < KVALID) {
            int ar = a / 25, ac = a % 25;
            int i, dy, j, dx;
            dec25(ar, i, dy);
            dec25(ac, j, dx);
            ij[s] = i * 7 + j;
            yx[s] = dy * 7 + dx;
        } else { ij[s] = 0; yx[s] = 0; }
    }

    float acc0 = 0.f, acc1 = 0.f, acc2 = 0.f;

    for (int cc = 0; cc < 4; ++cc) {
        __syncthreads();   // protect LDS from previous chunk's readers
        const float4* g1 = (const float4*)(P1 + cc * 64 * RR);
        const float4* g2 = (const float4*)(P2 + cc * 64 * RR);
        float4* l1 = (float4*)s1;
        float4* l2 = (float4*)s2;
        for (int i = t; i < (64 * RR) / 4; i += 256) { l1[i] = g1[i]; l2[i] = g2[i]; }
        __syncthreads();

        #pragma unroll 4
        for (int c = 0; c < 64; ++c) {
            const float* r1 = s1 + c * RR;
            const float* r2 = s2 + c * RR;
            acc0 = fmaf(r1[ij[0]], r2[yx[0]], acc0);
            acc1 = fmaf(r1[ij[1]], r2[yx[1]], acc1);
            acc2 = fmaf(r1[ij[2]], r2[yx[2]], acc2);
        }
    }

    float* row = xo + (size_t)b * KPAD;
    row[t]       = acc0;
    row[t + 256] = acc1;
    if (t < 128) row[t + 512] = (t < (KVALID - 512)) ? acc2 : 0.f;
}

// ---------------------------------------------------------------------------
// Split x fp32 -> bf16 hi/lo planes.
// ---------------------------------------------------------------------------
__global__ __launch_bounds__(256) void split_x_kernel(
    const float* __restrict__ xf,
    unsigned short* __restrict__ xh, unsigned short* __restrict__ xl)
{
    int idx = (blockIdx.x * 256 + threadIdx.x) * 4;   // over BATCH*KPAD
    float4 v = *(const float4*)&xf[idx];
    unsigned short h0, l0, h1, l1, h2, l2, h3, l3;
    split2(v.x, h0, l0); split2(v.y, h1, l1);
    split2(v.z, h2, l2); split2(v.w, h3, l3);
    *(ushort4*)&xh[idx] = make_ushort4(h0, h1, h2, h3);
    *(ushort4*)&xl[idx] = make_ushort4(l0, l1, l2, l3);
}

// ---------------------------------------------------------------------------
// Prep: gather W1 columns + split  -> w1h/w1l [REP_N x KPAD]
// ---------------------------------------------------------------------------
__global__ __launch_bounds__(256) void prep_w1_kernel(
    const float* __restrict__ W1,
    unsigned short* __restrict__ wh, unsigned short* __restrict__ wl)
{
    int idx = blockIdx.x * 256 + threadIdx.x;   // over REP_N*KPAD
    int n = idx / KPAD, a = idx - n * KPAD;
    float v = 0.f;
    if (a < KVALID) v = W1[(size_t)n * SP + kflat_of(a)];
    unsigned short h, l;
    split2(v, h, l);
    wh[idx] = h; wl[idx] = l;
}

// ---------------------------------------------------------------------------
// Prep: split W2 -> w2h/w2l [REP_N x REP_N]
// ---------------------------------------------------------------------------
__global__ __launch_bounds__(256) void prep_w2_kernel(
    const float* __restrict__ W2,
    unsigned short* __restrict__ wh, unsigned short* __restrict__ wl)
{
    int idx = (blockIdx.x * 256 + threadIdx.x) * 4;
    float4 v = *(const float4*)&W2[idx];
    unsigned short h0, l0, h1, l1, h2, l2, h3, l3;
    split2(v.x, h0, l0); split2(v.y, h1, l1);
    split2(v.z, h2, l2); split2(v.w, h3, l3);
    *(ushort4*)&wh[idx] = make_ushort4(h0, h1, h2, h3);
    *(ushort4*)&wl[idx] = make_ushort4(l0, l1, l2, l3);
}

// ---------------------------------------------------------------------------
// MFMA GEMM: Y[m,n] = relu( sum_k X[m,k]*W[n,k] + bias[n] )
// X,W as bf16 hi/lo planes; products hh + hl + lh. 64x64 tile, BK=64,
// 4 waves (2x2), each wave 32x32 = 2x2 16x16x32 fragments.
// ---------------------------------------------------------------------------
#define MM(d, a, b) d = __builtin_amdgcn_mfma_f32_16x16x32_bf16(a, b, d, 0, 0, 0)

template<bool SPLIT_OUT>
__global__ __launch_bounds__(256) void gemm_mfma(
    const unsigned short* __restrict__ Xh, const unsigned short* __restrict__ Xl, int ldx,
    const unsigned short* __restrict__ Wh, const unsigned short* __restrict__ Wl, int ldw,
    const float* __restrict__ bias, int K,
    float* __restrict__ Yf, unsigned short* __restrict__ Yh, unsigned short* __restrict__ Yl,
    int ldy)
{
    __shared__ unsigned short As[2][64][72];
    __shared__ unsigned short Bs[2][64][72];

    const int t = threadIdx.x;
    const int m_base = blockIdx.y * 64;
    const int n_base = blockIdx.x * 64;

    const int trow = t >> 2;
    const int tc   = (t & 3) * 8;

    const unsigned short* xh_p = Xh + (size_t)(m_base + trow) * ldx + tc;
    const unsigned short* xl_p = Xl + (size_t)(m_base + trow) * ldx + tc;
    const unsigned short* wh_p = Wh + (size_t)(n_base + trow) * ldw + tc;
    const unsigned short* wl_p = Wl + (size_t)(n_base + trow) * ldw + tc;

    const int wv   = t >> 6;
    const int lane = t & 63;
    const int wr = (wv >> 1) * 32;
    const int wc = (wv & 1) * 32;
    const int fr = lane & 15;
    const int fg = (lane >> 4) * 8;

    f32x4 acc00 = {}, acc01 = {}, acc10 = {}, acc11 = {};

    for (int k0 = 0; k0 < K; k0 += 64) {
        s16x8 vxh0 = *(const s16x8*)(xh_p + k0);
        s16x8 vxh1 = *(const s16x8*)(xh_p + k0 + 32);
        s16x8 vxl0 = *(const s16x8*)(xl_p + k0);
        s16x8 vxl1 = *(const s16x8*)(xl_p + k0 + 32);
        s16x8 vwh0 = *(const s16x8*)(wh_p + k0);
        s16x8 vwh1 = *(const s16x8*)(wh_p + k0 + 32);
        s16x8 vwl0 = *(const s16x8*)(wl_p + k0);
        s16x8 vwl1 = *(const s16x8*)(wl_p + k0 + 32);
        __syncthreads();
        *(s16x8*)&As[0][trow][tc]      = vxh0;
        *(s16x8*)&As[0][trow][tc + 32] = vxh1;
        *(s16x8*)&As[1][trow][tc]      = vxl0;
        *(s16x8*)&As[1][trow][tc + 32] = vxl1;
        *(s16x8*)&Bs[0][trow][tc]      = vwh0;
        *(s16x8*)&Bs[0][trow][tc + 32] = vwh1;
        *(s16x8*)&Bs[1][trow][tc]      = vwl0;
        *(s16x8*)&Bs[1][trow][tc + 32] = vwl1;
        __syncthreads();

        #pragma unroll
        for (int ks = 0; ks < 2; ++ks) {
            const int ko = ks * 32 + fg;
            s16x8 ah0 = *(const s16x8*)&As[0][wr + fr][ko];
            s16x8 ah1 = *(const s16x8*)&As[0][wr + 16 + fr][ko];
            s16x8 al0 = *(const s16x8*)&As[1][wr + fr][ko];
            s16x8 al1 = *(const s16x8*)&As[1][wr + 16 + fr][ko];
            s16x8 bh0 = *(const s16x8*)&Bs[0][wc + fr][ko];
            s16x8 bh1 = *(const s16x8*)&Bs[0][wc + 16 + fr][ko];
            s16x8 bl0 = *(const s16x8*)&Bs[1][wc + fr][ko];
            s16x8 bl1 = *(const s16x8*)&Bs[1][wc + 16 + fr][ko];

            MM(acc00, ah0, bh0); MM(acc00, ah0, bl0); MM(acc00, al0, bh0);
            MM(acc01, ah0, bh1); MM(acc01, ah0, bl1); MM(acc01, al0, bh1);
            MM(acc10, ah1, bh0); MM(acc10, ah1, bl0); MM(acc10, al1, bh0);
            MM(acc11, ah1, bh1); MM(acc11, ah1, bl1); MM(acc11, al1, bh1);
        }
    }

    const int arow = (lane >> 4) * 4;
    #pragma unroll
    for (int nf = 0; nf < 2; ++nf) {
        const int col = n_base + wc + nf * 16 + fr;
        const float bv = bias[col];
        #pragma unroll
        for (int mf = 0; mf < 2; ++mf) {
            const f32x4 a = (nf == 0) ? (mf == 0 ? acc00 : acc10)
                                      : (mf == 0 ? acc01 : acc11);
            #pragma unroll
            for (int r = 0; r < 4; ++r) {
                const int row = m_base + wr + mf * 16 + arow + r;
                float v = fmaxf(a[r] + bv, 0.f);
                if (SPLIT_OUT) {
                    unsigned short h, l;
                    split2(v, h, l);
                    Yh[(size_t)row * ldy + col] = h;
                    Yl[(size_t)row * ldy + col] = l;
                } else {
                    Yf[(size_t)row * ldy + col] = v;
                }
            }
        }
    }
}

// ---------------------------------------------------------------------------
// Head: out[b,:] = h2[b,:] @ W3.T + b3
// ---------------------------------------------------------------------------
__global__ __launch_bounds__(256) void head_kernel(
    const float* __restrict__ h2, const float* __restrict__ W3,
    const float* __restrict__ b3, float* __restrict__ out)
{
    const int b = blockIdx.x;
    const int t = threadIdx.x;
    const float* row = h2 + (size_t)b * REP_N;

    float a0 = 0.f, a1 = 0.f, a2 = 0.f, a3 = 0.f;
    for (int k = t; k < REP_N; k += 256) {
        float x = row[k];
        a0 = fmaf(x, W3[k],             a0);
        a1 = fmaf(x, W3[REP_N + k],     a1);
        a2 = fmaf(x, W3[2 * REP_N + k], a2);
        a3 = fmaf(x, W3[3 * REP_N + k], a3);
    }
    #pragma unroll
    for (int off = 32; off > 0; off >>= 1) {
        a0 += __shfl_down(a0, off);
        a1 += __shfl_down(a1, off);
        a2 += __shfl_down(a2, off);
        a3 += __shfl_down(a3, off);
    }
    __shared__ float red[4][4];
    int wid = t >> 6, lane = t & 63;
    if (lane == 0) { red[wid][0] = a0; red[wid][1] = a1; red[wid][2] = a2; red[wid][3] = a3; }
    __syncthreads();
    if (t < 4) {
        out[b * 4 + t] = red[0][t] + red[1][t] + red[2][t] + red[3][t] + b3[t];
    }
}

extern "C" void kernel_launch(void* const* d_in, const int* in_sizes, int n_in,
                              void* d_out, int out_size, void* d_ws, size_t ws_size,
                              hipStream_t stream) {
    const float* p1 = (const float*)d_in[0];
    const float* p2 = (const float*)d_in[1];
    const float* W1 = (const float*)d_in[2];
    const float* b1 = (const float*)d_in[3];
    const float* W2 = (const float*)d_in[4];
    const float* b2 = (const float*)d_in[5];
    const float* W3 = (const float*)d_in[6];
    const float* b3 = (const float*)d_in[7];
    float* out = (float*)d_out;

    char* ws = (char*)d_ws;
    unsigned short* xh  = (unsigned short*)(ws + 0);         // 1.31 MB
    unsigned short* xl  = (unsigned short*)(ws + 1310720);   // 1.31 MB
    unsigned short* w1h = (unsigned short*)(ws + 2621440);   // 1.31 MB
    unsigned short* w1l = (unsigned short*)(ws + 3932160);   // 1.31 MB
    float*          h2  = (float*)(ws + 0);                  // 4.19 MB (reuse after GEMM1)
    unsigned short* h1h = (unsigned short*)(ws + 5242880);   // 2.10 MB
    unsigned short* h1l = (unsigned short*)(ws + 7340032);   // 2.10 MB
    unsigned short* w2h = (unsigned short*)(ws + 9437184);   // 2.10 MB
    unsigned short* w2l = (unsigned short*)(ws + 11534336);  // 2.10 MB
    float*          xf  = (float*)(ws + 13631488);           // 2.62 MB (fp32 x)
    // total 16.25 MB

    corr_kernel<<<BATCH, 256, 0, stream>>>(p1, p2, xf);
    prep_w1_kernel<<<(REP_N * KPAD) / 256, 256, 0, stream>>>(W1, w1h, w1l);
    prep_w2_kernel<<<(REP_N * REP_N) / (256 * 4), 256, 0, stream>>>(W2, w2h, w2l);
    split_x_kernel<<<(BATCH * KPAD) / (256 * 4), 256, 0, stream>>>(xf, xh, xl);

    gemm_mfma<true><<<dim3(16, 16), 256, 0, stream>>>(
        xh, xl, KPAD, w1h, w1l, KPAD, b1, KPAD,
        (float*)nullptr, h1h, h1l, REP_N);

    gemm_mfma<false><<<dim3(16, 16), 256, 0, stream>>>(
        h1h, h1l, REP_N, w2h, w2l, REP_N, b2, REP_N,
        h2, (unsigned short*)nullptr, (unsigned short*)nullptr, REP_N);

    head_kernel<<<BATCH, 256, 0, stream>>>(h2, W3, b3, out);
}

// Round 9
// 66.417 us; speedup vs baseline: 1.2614x; 1.2614x over previous
//
#include <hip/hip_runtime.h>

// Problem constants
#define BATCH 1024
#define RR    49        // 7*7 spatial
#define SP    12544     // 256*49 per-batch patch elems; also FLAT
#define KVALID 625      // nonzero correlation outputs per batch
#define KPAD   640      // padded K for GEMM1
#define REP_N  1024
#define LP    53        // corr LDS pitch (floats): 53%32=21 -> <=2-way on frag reads

typedef __attribute__((ext_vector_type(4))) float f32x4;
typedef __attribute__((ext_vector_type(8))) short s16x8;   // 8 bf16 (4 VGPRs)

// ---- bf16 split helpers (RNE) ----
__device__ __forceinline__ unsigned short f2bf_rne(float f) {
    unsigned int u = __float_as_uint(f);
    unsigned int r = u + 0x7FFFu + ((u >> 16) & 1u);
    return (unsigned short)(r >> 16);
}
__device__ __forceinline__ float bf2f(unsigned short h) {
    return __uint_as_float(((unsigned int)h) << 16);
}
__device__ __forceinline__ void split2(float v, unsigned short& h, unsigned short& l) {
    h = f2bf_rne(v);
    l = f2bf_rne(v - bf2f(h));
}
// Pack two floats to bf16 pair (verified numerically R4-R8).
__device__ __forceinline__ unsigned int cvtpk_bf16(float a, float b) {
    unsigned int r;
    asm("v_cvt_pk_bf16_f32 %0, %1, %2" : "=v"(r) : "v"(a), "v"(b));
    return r;
}
// Split 8 floats -> hi/lo s16x8 fragments.
__device__ __forceinline__ void cvt8(const float* v, s16x8& hv, s16x8& lv) {
    unsigned int* hp = (unsigned int*)&hv;
    unsigned int* lp = (unsigned int*)&lv;
    #pragma unroll
    for (int i = 0; i < 4; ++i) {
        float v0 = v[2 * i], v1 = v[2 * i + 1];
        unsigned int ph = cvtpk_bf16(v0, v1);
        float h0 = __uint_as_float(ph << 16);
        float h1 = __uint_as_float(ph & 0xFFFF0000u);
        unsigned int pl = cvtpk_bf16(v0 - h0, v1 - h1);
        hp[i] = ph; lp[i] = pl;
    }
}

// Decode index u in [0,25) -> (i, d), i,d in [0,7), i+d even.
__device__ __forceinline__ void dec25(int u, int& i, int& d) {
    int ii = (u >= 4) + (u >= 7) + (u >= 11) + (u >= 14) + (u >= 18) + (u >= 21);
    int cum = (7 * ii + 1) >> 1;
    i = ii;
    d = 2 * (u - cum) + (ii & 1);
}
// Encode (i,d) -> [0,25), inverse of dec25.
__device__ __forceinline__ int enc25(int i, int d) {
    return ((7 * i + 1) >> 1) + ((d - (i & 1)) >> 1);
}

// Compact index a in [0,640) -> flat column into W1's FLAT dim (a>=625 unused).
__device__ __forceinline__ int kflat_of(int a) {
    int ar = a / 25, ac = a % 25;
    int i, dy, j, dx;
    dec25(ar, i, dy);
    dec25(ac, j, dx);
    int pi = (dy + 16 - i) >> 1;
    int pj = (dx + 16 - j) >> 1;
    return (pi * 16 + pj) * 49 + i * 7 + j;
}

#define MM(d, a, b) d = __builtin_amdgcn_mfma_f32_16x16x32_bf16(a, b, d, 0, 0, 0)

// ---------------------------------------------------------------------------
// Kernel 1: correlation via parity-block-diagonal Gram.
// Valid (s1,s2) pairs require i==dy, j==dx (mod 2), so in parity-class order
// the Gram is block-diagonal: classes (ci,cj) of sizes 16/12/12/9 and
// 16^2+12^2+12^2+9^2 = 625 = exactly the valid outputs.
// One block = one batch; wave c computes class c as ONE 16x16x32-MFMA chain
// (split-bf16 hh+hl+lh, f32x4 accumulator) over K=256 in 4 chunks of 64ch.
// Staging: coalesced float4 global -> [ch][53] fp32 LDS (conflict-free
// writes, <=2-way frag reads); register prefetch of chunk cc+1.
// ---------------------------------------------------------------------------
__global__ __launch_bounds__(256) void corr_parity_kernel(
    const float* __restrict__ p1, const float* __restrict__ p2,
    unsigned short* __restrict__ xh, unsigned short* __restrict__ xl)
{
    __shared__ float T1[64 * LP];          // 13.6 KB [ch][s]
    __shared__ float T2[64 * LP];
    __shared__ unsigned short SXh[KPAD];   // compact output staging
    __shared__ unsigned short SXl[KPAD];

    const int b = blockIdx.x;
    const int t = threadIdx.x;
    const float* P1 = p1 + (size_t)b * SP;
    const float* P2 = p2 + (size_t)b * SP;

    const int wv   = t >> 6;
    const int lane = t & 63;
    const int fr   = lane & 15;        // class-pos index (A row / B col)
    const int fg   = (lane >> 4) * 8;  // k-offset within 32-chunk

    // class geometry: ci,cj = parities; ni x nj positions
    const int ci = wv >> 1, cj = wv & 1;
    const int nj = 4 - cj;                   // cols per class row
    const int clsN = (4 - ci) * nj;          // 16 / 12 / 12 / 9
    const int pr = (fr < clsN) ? fr : 0;     // clamp dead lanes
    const int sPos = (2 * (pr / nj) + ci) * 7 + (2 * (pr % nj) + cj);

    // zero output staging (covers pad 625..639; classes are disjoint)
    for (int i = t; i < KPAD; i += 256) { SXh[i] = 0; SXl[i] = 0; }

    // ---- prefetch chunk 0: 784 float4 per tensor, fully coalesced
    float4 f1[4], f2[4];
    #pragma unroll
    for (int q = 0; q < 4; ++q) {
        const int qi = t + q * 256;
        if (qi < 784) {
            f1[q] = ((const float4*)P1)[qi];
            f2[q] = ((const float4*)P2)[qi];
        }
    }

    f32x4 acc = {};

    for (int cc = 0; cc < 4; ++cc) {
        __syncthreads();   // previous chunk's readers done
        // scatter prefetched float4s into [ch][53] tiles (consecutive banks)
        #pragma unroll
        for (int q = 0; q < 4; ++q) {
            const int qi = t + q * 256;
            if (qi < 784) {
                const int gg = qi * 4;
                const float v1[4] = {f1[q].x, f1[q].y, f1[q].z, f1[q].w};
                const float v2[4] = {f2[q].x, f2[q].y, f2[q].z, f2[q].w};
                #pragma unroll
                for (int e = 0; e < 4; ++e) {
                    const int ch = (gg + e) / 49;
                    const int s  = (gg + e) - ch * 49;
                    T1[ch * LP + s] = v1[e];
                    T2[ch * LP + s] = v2[e];
                }
            }
        }
        __syncthreads();   // tiles ready

        // issue next chunk's loads; latency hides under compute
        if (cc < 3) {
            const float4* G1 = (const float4*)(P1 + (cc + 1) * 3136);
            const float4* G2 = (const float4*)(P2 + (cc + 1) * 3136);
            #pragma unroll
            for (int q = 0; q < 4; ++q) {
                const int qi = t + q * 256;
                if (qi < 784) { f1[q] = G1[qi]; f2[q] = G2[qi]; }
            }
        }

        // compute: 2 k-steps x (16 ds_read_b32 + 2 cvt8 + 3 MFMA)
        #pragma unroll
        for (int ks = 0; ks < 2; ++ks) {
            const int kb = (ks * 32 + fg) * LP + sPos;
            float av[8], bv[8];
            #pragma unroll
            for (int i = 0; i < 8; ++i) {
                av[i] = T1[kb + i * LP];
                bv[i] = T2[kb + i * LP];
            }
            s16x8 ah, al, bh, bl;
            cvt8(av, ah, al);
            cvt8(bv, bh, bl);
            MM(acc, ah, bh);
            MM(acc, ah, bl);
            MM(acc, al, bh);
        }
    }

    // Epilogue: C/D layout col = lane&15 (s2 class-pos), row = 4*(lane>>4)+r
    // (s1 class-pos). Map class-pos -> (i,j)/(dy,dx) -> compact x index.
    const int arow = (lane >> 4) * 4;
    if (fr < clsN) {
        const int dy = 2 * (fr / nj) + ci;
        const int dx = 2 * (fr % nj) + cj;
        #pragma unroll
        for (int r = 0; r < 4; ++r) {
            const int rowp = arow + r;
            if (rowp < clsN) {
                const int i1 = 2 * (rowp / nj) + ci;
                const int j1 = 2 * (rowp % nj) + cj;
                const int aidx = enc25(i1, dy) * 25 + enc25(j1, dx);
                unsigned short h, l;
                split2(acc[r], h, l);
                SXh[aidx] = h; SXl[aidx] = l;
            }
        }
    }
    __syncthreads();

    unsigned int* rh = (unsigned int*)(xh + (size_t)b * KPAD);
    unsigned int* rl = (unsigned int*)(xl + (size_t)b * KPAD);
    const unsigned int* sh = (const unsigned int*)SXh;
    const unsigned int* sl = (const unsigned int*)SXl;
    for (int i = t; i < KPAD / 2; i += 256) { rh[i] = sh[i]; rl[i] = sl[i]; }
}

// ---------------------------------------------------------------------------
// Prep: gather W1 columns + split  -> w1h/w1l [REP_N x KPAD]
// ---------------------------------------------------------------------------
__global__ __launch_bounds__(256) void prep_w1_kernel(
    const float* __restrict__ W1,
    unsigned short* __restrict__ wh, unsigned short* __restrict__ wl)
{
    int idx = blockIdx.x * 256 + threadIdx.x;   // over REP_N*KPAD
    int n = idx / KPAD, a = idx - n * KPAD;
    float v = 0.f;
    if (a < KVALID) v = W1[(size_t)n * SP + kflat_of(a)];
    unsigned short h, l;
    split2(v, h, l);
    wh[idx] = h; wl[idx] = l;
}

// ---------------------------------------------------------------------------
// Prep: split W2 -> w2h/w2l [REP_N x REP_N]
// ---------------------------------------------------------------------------
__global__ __launch_bounds__(256) void prep_w2_kernel(
    const float* __restrict__ W2,
    unsigned short* __restrict__ wh, unsigned short* __restrict__ wl)
{
    int idx = (blockIdx.x * 256 + threadIdx.x) * 4;
    float4 v = *(const float4*)&W2[idx];
    unsigned short h0, l0, h1, l1, h2, l2, h3, l3;
    split2(v.x, h0, l0); split2(v.y, h1, l1);
    split2(v.z, h2, l2); split2(v.w, h3, l3);
    *(ushort4*)&wh[idx] = make_ushort4(h0, h1, h2, h3);
    *(ushort4*)&wl[idx] = make_ushort4(l0, l1, l2, l3);
}

// ---------------------------------------------------------------------------
// MFMA GEMM: Y[m,n] = relu( sum_k X[m,k]*W[n,k] + bias[n] )
// X,W as bf16 hi/lo planes; products hh + hl + lh. 64x64 tile, BK=64,
// 4 waves (2x2), each wave 32x32 = 2x2 16x16x32 fragments.
// ---------------------------------------------------------------------------
template<bool SPLIT_OUT>
__global__ __launch_bounds__(256) void gemm_mfma(
    const unsigned short* __restrict__ Xh, const unsigned short* __restrict__ Xl, int ldx,
    const unsigned short* __restrict__ Wh, const unsigned short* __restrict__ Wl, int ldw,
    const float* __restrict__ bias, int K,
    float* __restrict__ Yf, unsigned short* __restrict__ Yh, unsigned short* __restrict__ Yl,
    int ldy)
{
    __shared__ unsigned short As[2][64][72];
    __shared__ unsigned short Bs[2][64][72];

    const int t = threadIdx.x;
    const int m_base = blockIdx.y * 64;
    const int n_base = blockIdx.x * 64;

    const int trow = t >> 2;
    const int tc   = (t & 3) * 8;

    const unsigned short* xh_p = Xh + (size_t)(m_base + trow) * ldx + tc;
    const unsigned short* xl_p = Xl + (size_t)(m_base + trow) * ldx + tc;
    const unsigned short* wh_p = Wh + (size_t)(n_base + trow) * ldw + tc;
    const unsigned short* wl_p = Wl + (size_t)(n_base + trow) * ldw + tc;

    const int wv   = t >> 6;
    const int lane = t & 63;
    const int wr = (wv >> 1) * 32;
    const int wc = (wv & 1) * 32;
    const int fr = lane & 15;
    const int fg = (lane >> 4) * 8;

    f32x4 acc00 = {}, acc01 = {}, acc10 = {}, acc11 = {};

    for (int k0 = 0; k0 < K; k0 += 64) {
        s16x8 vxh0 = *(const s16x8*)(xh_p + k0);
        s16x8 vxh1 = *(const s16x8*)(xh_p + k0 + 32);
        s16x8 vxl0 = *(const s16x8*)(xl_p + k0);
        s16x8 vxl1 = *(const s16x8*)(xl_p + k0 + 32);
        s16x8 vwh0 = *(const s16x8*)(wh_p + k0);
        s16x8 vwh1 = *(const s16x8*)(wh_p + k0 + 32);
        s16x8 vwl0 = *(const s16x8*)(wl_p + k0);
        s16x8 vwl1 = *(const s16x8*)(wl_p + k0 + 32);
        __syncthreads();
        *(s16x8*)&As[0][trow][tc]      = vxh0;
        *(s16x8*)&As[0][trow][tc + 32] = vxh1;
        *(s16x8*)&As[1][trow][tc]      = vxl0;
        *(s16x8*)&As[1][trow][tc + 32] = vxl1;
        *(s16x8*)&Bs[0][trow][tc]      = vwh0;
        *(s16x8*)&Bs[0][trow][tc + 32] = vwh1;
        *(s16x8*)&Bs[1][trow][tc]      = vwl0;
        *(s16x8*)&Bs[1][trow][tc + 32] = vwl1;
        __syncthreads();

        #pragma unroll
        for (int ks = 0; ks < 2; ++ks) {
            const int ko = ks * 32 + fg;
            s16x8 ah0 = *(const s16x8*)&As[0][wr + fr][ko];
            s16x8 ah1 = *(const s16x8*)&As[0][wr + 16 + fr][ko];
            s16x8 al0 = *(const s16x8*)&As[1][wr + fr][ko];
            s16x8 al1 = *(const s16x8*)&As[1][wr + 16 + fr][ko];
            s16x8 bh0 = *(const s16x8*)&Bs[0][wc + fr][ko];
            s16x8 bh1 = *(const s16x8*)&Bs[0][wc + 16 + fr][ko];
            s16x8 bl0 = *(const s16x8*)&Bs[1][wc + fr][ko];
            s16x8 bl1 = *(const s16x8*)&Bs[1][wc + 16 + fr][ko];

            MM(acc00, ah0, bh0); MM(acc00, ah0, bl0); MM(acc00, al0, bh0);
            MM(acc01, ah0, bh1); MM(acc01, ah0, bl1); MM(acc01, al0, bh1);
            MM(acc10, ah1, bh0); MM(acc10, ah1, bl0); MM(acc10, al1, bh0);
            MM(acc11, ah1, bh1); MM(acc11, ah1, bl1); MM(acc11, al1, bh1);
        }
    }

    const int arow = (lane >> 4) * 4;
    #pragma unroll
    for (int nf = 0; nf < 2; ++nf) {
        const int col = n_base + wc + nf * 16 + fr;
        const float bv = bias[col];
        #pragma unroll
        for (int mf = 0; mf < 2; ++mf) {
            const f32x4 a = (nf == 0) ? (mf == 0 ? acc00 : acc10)
                                      : (mf == 0 ? acc01 : acc11);
            #pragma unroll
            for (int r = 0; r < 4; ++r) {
                const int row = m_base + wr + mf * 16 + arow + r;
                float v = fmaxf(a[r] + bv, 0.f);
                if (SPLIT_OUT) {
                    unsigned short h, l;
                    split2(v, h, l);
                    Yh[(size_t)row * ldy + col] = h;
                    Yl[(size_t)row * ldy + col] = l;
                } else {
                    Yf[(size_t)row * ldy + col] = v;
                }
            }
        }
    }
}

// ---------------------------------------------------------------------------
// Head: out[b,:] = h2[b,:] @ W3.T + b3
// ---------------------------------------------------------------------------
__global__ __launch_bounds__(256) void head_kernel(
    const float* __restrict__ h2, const float* __restrict__ W3,
    const float* __restrict__ b3, float* __restrict__ out)
{
    const int b = blockIdx.x;
    const int t = threadIdx.x;
    const float* row = h2 + (size_t)b * REP_N;

    float a0 = 0.f, a1 = 0.f, a2 = 0.f, a3 = 0.f;
    for (int k = t; k < REP_N; k += 256) {
        float x = row[k];
        a0 = fmaf(x, W3[k],             a0);
        a1 = fmaf(x, W3[REP_N + k],     a1);
        a2 = fmaf(x, W3[2 * REP_N + k], a2);
        a3 = fmaf(x, W3[3 * REP_N + k], a3);
    }
    #pragma unroll
    for (int off = 32; off > 0; off >>= 1) {
        a0 += __shfl_down(a0, off);
        a1 += __shfl_down(a1, off);
        a2 += __shfl_down(a2, off);
        a3 += __shfl_down(a3, off);
    }
    __shared__ float red[4][4];
    int wid = t >> 6, lane = t & 63;
    if (lane == 0) { red[wid][0] = a0; red[wid][1] = a1; red[wid][2] = a2; red[wid][3] = a3; }
    __syncthreads();
    if (t < 4) {
        out[b * 4 + t] = red[0][t] + red[1][t] + red[2][t] + red[3][t] + b3[t];
    }
}

extern "C" void kernel_launch(void* const* d_in, const int* in_sizes, int n_in,
                              void* d_out, int out_size, void* d_ws, size_t ws_size,
                              hipStream_t stream) {
    const float* p1 = (const float*)d_in[0];
    const float* p2 = (const float*)d_in[1];
    const float* W1 = (const float*)d_in[2];
    const float* b1 = (const float*)d_in[3];
    const float* W2 = (const float*)d_in[4];
    const float* b2 = (const float*)d_in[5];
    const float* W3 = (const float*)d_in[6];
    const float* b3 = (const float*)d_in[7];
    float* out = (float*)d_out;

    char* ws = (char*)d_ws;
    unsigned short* xh  = (unsigned short*)(ws + 0);         // 1.31 MB
    unsigned short* xl  = (unsigned short*)(ws + 1310720);   // 1.31 MB
    unsigned short* w1h = (unsigned short*)(ws + 2621440);   // 1.31 MB
    unsigned short* w1l = (unsigned short*)(ws + 3932160);   // 1.31 MB
    float*          h2  = (float*)(ws + 0);                  // 4.19 MB (reuse after GEMM1)
    unsigned short* h1h = (unsigned short*)(ws + 5242880);   // 2.10 MB
    unsigned short* h1l = (unsigned short*)(ws + 7340032);   // 2.10 MB
    unsigned short* w2h = (unsigned short*)(ws + 9437184);   // 2.10 MB
    unsigned short* w2l = (unsigned short*)(ws + 11534336);  // 2.10 MB

    corr_parity_kernel<<<BATCH, 256, 0, stream>>>(p1, p2, xh, xl);
    prep_w1_kernel<<<(REP_N * KPAD) / 256, 256, 0, stream>>>(W1, w1h, w1l);
    prep_w2_kernel<<<(REP_N * REP_N) / (256 * 4), 256, 0, stream>>>(W2, w2h, w2l);

    gemm_mfma<true><<<dim3(16, 16), 256, 0, stream>>>(
        xh, xl, KPAD, w1h, w1l, KPAD, b1, KPAD,
        (float*)nullptr, h1h, h1l, REP_N);

    gemm_mfma<false><<<dim3(16, 16), 256, 0, stream>>>(
        h1h, h1l, REP_N, w2h, w2l, REP_N, b2, REP_N,
        h2, (unsigned short*)nullptr, (unsigned short*)nullptr, REP_N);

    head_kernel<<<BATCH, 256, 0, stream>>>(h2, W3, b3, out);
}